// Round 14
// baseline (21.941 us; speedup 1.0000x reference)
//
#include <hip/hip_runtime.h>

#define DEV __device__ __forceinline__

// One wave (64 lanes) simulates one sample's 1024-amplitude state.
// flat idx = lane*16 + j ; wire w <-> flat bit (9-w):
//   wires 0..5 -> lane bits 5..0 (masks 32,16,8,4,2,1)
//   wires 6..8 -> packed-slot jj bits 2..0 (masks 4,2,1);  wire 9 -> component
// State: f2 re[8], im[8] (packed fp32, v_pk_fma_f32 full-rate).
//
// R10: CNOT chains never materialized (PHI frame change).
// R11: wave-uniform trig/matrix building once per block into LDS.
// R13: layer-1 Rots folded into the encoding product state.
// R14: swizzle->DPP conversions (masks 3,6,10,5), tree-reassociated product
//      build, Z-feature coefficient fold, __launch_bounds__(256,4).

typedef float f2 __attribute__((ext_vector_type(2)));

DEV float shx(float v, int m) { return __shfl_xor(v, m, 64); }

template <int CTRL>
DEV float dppx(float x) {
  int xi = __builtin_bit_cast(int, x);
  return __builtin_bit_cast(
      float, __builtin_amdgcn_update_dpp(xi, xi, CTRL, 0xF, 0xF, false));
}
template <int OFS>
DEV float swz(float x) {
  return __builtin_bit_cast(
      float, __builtin_amdgcn_ds_swizzle(__builtin_bit_cast(int, x), OFS));
}

// DPP ctrls: quad_perm xor1=0xB1, xor2=0x4E, xor3=0x1B;
//            row_ror:8 = 0x128 (xor8); row_half_mirror = 0x141 (xor7).

template <int M>  // scalar value at lane^M (single-bit masks)
DEV float partner(float x) {
  if constexpr (M == 32) return shx(x, 32);
  else if constexpr (M == 16) return swz<0x401F>(x);
  else if constexpr (M == 8) return dppx<0x128>(x);
  else if constexpr (M == 4) return swz<0x101F>(x);
  else if constexpr (M == 2) return dppx<0x4E>(x);
  else return dppx<0xB1>(x);
}
template <int M>
DEV f2 partner2(f2 v) { return (f2){partner<M>(v.x), partner<M>(v.y)}; }

template <int XM>  // generic lane-xor exchange (multi-bit masks)
DEV float lanex(float x) {
  if constexpr (XM == 48) return shx(x, 48);
  else if constexpr (XM == 40) return shx(x, 40);
  else if constexpr (XM == 24) return swz<0x601F>(x);
  else if constexpr (XM == 20) return swz<0x501F>(x);
  else if constexpr (XM == 12) return swz<0x301F>(x);
  else if constexpr (XM == 10) return dppx<0x4E>(dppx<0x128>(x));   // xor8∘xor2
  else if constexpr (XM == 6)  return dppx<0xB1>(dppx<0x141>(x));   // xor7∘xor1
  else if constexpr (XM == 5)  return dppx<0x4E>(dppx<0x141>(x));   // xor7∘xor2
  else if constexpr (XM == 3)  return dppx<0x1B>(x);                // quad xor3
}
template <int XM>
DEV f2 lanex2(f2 v) { return (f2){lanex<XM>(v.x), lanex<XM>(v.y)}; }

DEV f2 swp(f2 v) { return (f2){v.y, v.x}; }

// ================= layer-2 gates (conjugated by PHI, verified R10/R12) =======

template <int XM, int SELM>
DEV void rot2_lane(f2 (&re)[8], f2 (&im)[8], int lane,
                   float u00r, float u00i, float u01r, float u01i,
                   float u10r, float u10i, float u11r, float u11i) {
  const bool hi = (__popc(lane & SELM) & 1) != 0;
  float Dor = hi ? u11r : u00r, Doi = hi ? u11i : u00i;
  float Dpr = hi ? u10r : u01r, Dpi = hi ? u10i : u01i;
#pragma unroll
  for (int jj = 0; jj < 8; ++jj) {
    f2 pr = lanex2<XM>(re[jj]), pi = lanex2<XM>(im[jj]);
    f2 nr = Dor * re[jj] - Doi * im[jj] + Dpr * pr - Dpi * pi;
    f2 ni = Dor * im[jj] + Doi * re[jj] + Dpr * pi + Dpi * pr;
    re[jj] = nr; im[jj] = ni;
  }
}

DEV void rot2_w5(f2 (&re)[8], f2 (&im)[8], bool p5,
                 float u00r, float u00i, float u01r, float u01i,
                 float u10r, float u10i, float u11r, float u11i) {
  float Dor = p5 ? u11r : u00r, Doi = p5 ? u11i : u00i;
  float Dpr = p5 ? u10r : u01r, Dpi = p5 ? u10i : u01i;
  f2 o_r[8], o_i[8];
#pragma unroll
  for (int jj = 0; jj < 8; ++jj) { o_r[jj] = re[jj]; o_i[jj] = im[jj]; }
#pragma unroll
  for (int jj = 0; jj < 8; ++jj) {
    const int k = jj ^ 4;
    f2 pr = partner2<1>(o_r[k]), pi = partner2<1>(o_i[k]);
    re[jj] = Dor * o_r[jj] - Doi * o_i[jj] + Dpr * pr - Dpi * pi;
    im[jj] = Dor * o_i[jj] + Doi * o_r[jj] + Dpr * pi + Dpi * pr;
  }
}

template <int M2, int CLS>
DEV void rot2_local(f2 (&re)[8], f2 (&im)[8], bool p5,
                    float u00r, float u00i, float u01r, float u01i,
                    float u10r, float u10i, float u11r, float u11i) {
  const float D0or = p5 ? u11r : u00r, D0oi = p5 ? u11i : u00i;
  const float D0pr = p5 ? u10r : u01r, D0pi = p5 ? u10i : u01i;
  const float D1or = p5 ? u00r : u11r, D1oi = p5 ? u00i : u11i;
  const float D1pr = p5 ? u01r : u10r, D1pi = p5 ? u01i : u10i;
  f2 o_r[8], o_i[8];
#pragma unroll
  for (int jj = 0; jj < 8; ++jj) { o_r[jj] = re[jj]; o_i[jj] = im[jj]; }
#pragma unroll
  for (int jj = 0; jj < 8; ++jj) {
    const int k = jj ^ M2;
    const bool c1 = (__builtin_popcount(jj & CLS) & 1) != 0;
    const float Dor = c1 ? D1or : D0or, Doi = c1 ? D1oi : D0oi;
    const float Dpr = c1 ? D1pr : D0pr, Dpi = c1 ? D1pi : D0pi;
    re[jj] = Dor * o_r[jj] - Doi * o_i[jj] + Dpr * o_r[k] - Dpi * o_i[k];
    im[jj] = Dor * o_i[jj] + Doi * o_r[jj] + Dpr * o_i[k] + Dpi * o_r[k];
  }
}

DEV void rot2_w8(f2 (&re)[8], f2 (&im)[8], bool p5,
                 float u00r, float u00i, float u01r, float u01i,
                 float u10r, float u10i, float u11r, float u11i) {
  const float D0or = p5 ? u11r : u00r, D0oi = p5 ? u11i : u00i;
  const float D0pr = p5 ? u10r : u01r, D0pi = p5 ? u10i : u01i;
  const float D1or = p5 ? u00r : u11r, D1oi = p5 ? u00i : u11i;
  const float D1pr = p5 ? u01r : u10r, D1pi = p5 ? u01i : u10i;
  f2 o_r[8], o_i[8];
#pragma unroll
  for (int jj = 0; jj < 8; ++jj) { o_r[jj] = re[jj]; o_i[jj] = im[jj]; }
#pragma unroll
  for (int jj = 0; jj < 8; ++jj) {
    const int k = jj ^ 1;
    const bool c1 = (__builtin_popcount(jj & 7) & 1) != 0;
    const float Dor = c1 ? D1or : D0or, Doi = c1 ? D1oi : D0oi;
    const float Dpr = c1 ? D1pr : D0pr, Dpi = c1 ? D1pi : D0pi;
    f2 pr = swp(o_r[k]), pi = swp(o_i[k]);
    re[jj] = Dor * o_r[jj] - Doi * o_i[jj] + Dpr * pr - Dpi * pi;
    im[jj] = Dor * o_i[jj] + Doi * o_r[jj] + Dpr * pi + Dpi * pr;
  }
}

DEV void rot2_w9(f2 (&re)[8], f2 (&im)[8], bool p5,
                 float u00r, float u00i, float u01r, float u01i,
                 float u10r, float u10i, float u11r, float u11i) {
  const f2 Vor0 = p5 ? (f2){u11r, u00r} : (f2){u00r, u11r};
  const f2 Voi0 = p5 ? (f2){u11i, u00i} : (f2){u00i, u11i};
  const f2 Vpr0 = p5 ? (f2){u10r, u01r} : (f2){u01r, u10r};
  const f2 Vpi0 = p5 ? (f2){u10i, u01i} : (f2){u01i, u10i};
  const f2 Vor1 = p5 ? (f2){u00r, u11r} : (f2){u11r, u00r};
  const f2 Voi1 = p5 ? (f2){u00i, u11i} : (f2){u11i, u00i};
  const f2 Vpr1 = p5 ? (f2){u01r, u10r} : (f2){u10r, u01r};
  const f2 Vpi1 = p5 ? (f2){u01i, u10i} : (f2){u10i, u01i};
#pragma unroll
  for (int jj = 0; jj < 8; ++jj) {
    const bool c1 = (__builtin_popcount(jj) & 1) != 0;
    const f2 Vor = c1 ? Vor1 : Vor0, Voi = c1 ? Voi1 : Voi0;
    const f2 Vpr = c1 ? Vpr1 : Vpr0, Vpi = c1 ? Vpi1 : Vpi0;
    f2 sr = swp(re[jj]), si = swp(im[jj]);
    f2 nr = Vor * re[jj] - Voi * im[jj] + Vpr * sr - Vpi * si;
    f2 ni = Vor * im[jj] + Voi * re[jj] + Vpr * si + Vpi * sr;
    re[jj] = nr; im[jj] = ni;
  }
}

// ================= U-matrix build =============================================

DEV void make_u(const float* __restrict__ pp, float (&u)[8]) {
  // PennyLane Rot = RZ(om) @ RY(th) @ RZ(ph)
  float ph = pp[0], th = pp[1], om = pp[2];
  float s, c;   __sincosf(0.5f * th, &s, &c);
  float sa, ca; __sincosf(0.5f * (ph + om), &sa, &ca);
  float sb, cb; __sincosf(0.5f * (ph - om), &sb, &cb);
  u[0] = c * ca;  u[1] = -c * sa;   // u00
  u[2] = -s * cb; u[3] = -s * sb;   // u01
  u[4] = s * cb;  u[5] = -s * sb;   // u10
  u[6] = c * ca;  u[7] = c * sa;    // u11
}

DEV void rot2_wire(int w, f2 (&re)[8], f2 (&im)[8], int lane, bool p5,
                   const float* u) {
  float u00r = u[0], u00i = u[1], u01r = u[2], u01i = u[3];
  float u10r = u[4], u10i = u[5], u11r = u[6], u11i = u[7];
  switch (w) {
    case 0: rot2_lane<48, 32>(re, im, lane, u00r, u00i, u01r, u01i, u10r, u10i, u11r, u11i); break;
    case 1: rot2_lane<24, 48>(re, im, lane, u00r, u00i, u01r, u01i, u10r, u10i, u11r, u11i); break;
    case 2: rot2_lane<12, 56>(re, im, lane, u00r, u00i, u01r, u01i, u10r, u10i, u11r, u11i); break;
    case 3: rot2_lane<6, 60>(re, im, lane, u00r, u00i, u01r, u01i, u10r, u10i, u11r, u11i); break;
    case 4: rot2_lane<3, 62>(re, im, lane, u00r, u00i, u01r, u01i, u10r, u10i, u11r, u11i); break;
    case 5: rot2_w5(re, im, p5, u00r, u00i, u01r, u01i, u10r, u10i, u11r, u11i); break;
    case 6: rot2_local<6, 4>(re, im, p5, u00r, u00i, u01r, u01i, u10r, u10i, u11r, u11i); break;
    case 7: rot2_local<3, 6>(re, im, p5, u00r, u00i, u01r, u01i, u10r, u10i, u11r, u11i); break;
    case 8: rot2_w8(re, im, p5, u00r, u00i, u01r, u01i, u10r, u10i, u11r, u11i); break;
    case 9: rot2_w9(re, im, p5, u00r, u00i, u01r, u01i, u10r, u10i, u11r, u11i); break;
  }
}

// ================= X features (PHI^2 frame, verified R10/R12) ================

template <int XM>
DEV float xfeat_lane(const f2 (&re)[8], const f2 (&im)[8]) {
  f2 t = (f2){0.f, 0.f};
#pragma unroll
  for (int jj = 0; jj < 8; ++jj)
    t += re[jj] * lanex2<XM>(re[jj]) + im[jj] * lanex2<XM>(im[jj]);
  return t.x + t.y;
}

// ================= kernel ====================================================

__global__ __launch_bounds__(256, 4) void qreg_kernel(
    const float* __restrict__ x,      // (B, 10)
    const float* __restrict__ params, // (60,)
    const float* __restrict__ hw,     // (20,)
    const float* __restrict__ hb,     // (1,)
    float* __restrict__ out,          // (B,)
    int Bn) {
  const int tid = threadIdx.x;
  const int lane = tid & 63;
  const int wv = tid >> 6;
  const int b = blockIdx.x * 4 + wv;
  const bool p5 = (__popc(lane & 63) & 1) != 0;

  // ---- once-per-block precompute (LDS broadcast) ----
  __shared__ __align__(16) float Ulds[10][8];   // layer-2 Rot matrices
  __shared__ __align__(16) float Enc[4][10][4]; // per-sample g_w = U_w1 @ (c,s)

  if (tid < 10) {
    float u[8];
    make_u(params + (10 + tid) * 3, u);
#pragma unroll
    for (int k = 0; k < 8; ++k) Ulds[tid][k] = u[k];
  }
  if (tid >= 64 && tid < 104) {
    const int t = tid - 64;
    const int s = t / 10, w = t % 10;
    int bs = blockIdx.x * 4 + s;
    if (bs >= Bn) bs = Bn - 1;
    float sn, cs;
    __sincosf(0.5f * x[bs * 10 + w], &sn, &cs);
    float u[8];
    make_u(params + w * 3, u);  // layer-1 U for this wire
    // g = U @ (cs, sn)^T  (cs,sn real)
    Enc[s][w][0] = u[0] * cs + u[2] * sn;  // g0r
    Enc[s][w][1] = u[1] * cs + u[3] * sn;  // g0i
    Enc[s][w][2] = u[4] * cs + u[6] * sn;  // g1r
    Enc[s][w][3] = u[5] * cs + u[7] * sn;  // g1i
  }
  __syncthreads();

  f2 re[8], im[8];

  // ---- product state = encoding ⊗ layer-1 (complex factors) ----
  {
    float g0r[10], g0i[10], g1r[10], g1i[10];
#pragma unroll
    for (int w = 0; w < 10; ++w) {
      g0r[w] = Enc[wv][w][0]; g0i[w] = Enc[wv][w][1];
      g1r[w] = Enc[wv][w][2]; g1i[w] = Enc[wv][w][3];
    }
    // lane factor L (complex), tree-reassociated: wires 0..5 <-> lane bits 5..0
    float sr[6], si[6];
#pragma unroll
    for (int w = 0; w < 6; ++w) {
      const int m = 1 << (5 - w);
      sr[w] = (lane & m) ? g1r[w] : g0r[w];
      si[w] = (lane & m) ? g1i[w] : g0i[w];
    }
    float a01r = sr[0] * sr[1] - si[0] * si[1];
    float a01i = sr[0] * si[1] + si[0] * sr[1];
    float a23r = sr[2] * sr[3] - si[2] * si[3];
    float a23i = sr[2] * si[3] + si[2] * sr[3];
    float a45r = sr[4] * sr[5] - si[4] * si[5];
    float a45i = sr[4] * si[5] + si[4] * sr[5];
    float b03r = a01r * a23r - a01i * a23i;
    float b03i = a01r * a23i + a01i * a23r;
    float Lr = b03r * a45r - b03i * a45i;
    float Li = b03r * a45i + b03i * a45r;
    // m6[b6] = L * g6[b6]
    float m6r[2], m6i[2];
#pragma unroll
    for (int bq = 0; bq < 2; ++bq) {
      float ar = bq ? g1r[6] : g0r[6], ai = bq ? g1i[6] : g0i[6];
      m6r[bq] = Lr * ar - Li * ai;
      m6i[bq] = Lr * ai + Li * ar;
    }
    // m67[b6*2+b7] = m6[b6] * g7[b7]
    float m67r[4], m67i[4];
#pragma unroll
    for (int q = 0; q < 4; ++q) {
      const int b6 = q >> 1, b7 = q & 1;
      float ar = b7 ? g1r[7] : g0r[7], ai = b7 ? g1i[7] : g0i[7];
      m67r[q] = m6r[b6] * ar - m6i[b6] * ai;
      m67i[q] = m6r[b6] * ai + m6i[b6] * ar;
    }
    // P[jj] = m67[jj>>1] * g8[jj&1]; amp[jj] = P[jj] * g9(component pair)
    const f2 g9r = (f2){g0r[9], g1r[9]}, g9i = (f2){g0i[9], g1i[9]};
#pragma unroll
    for (int jj = 0; jj < 8; ++jj) {
      const int q = jj >> 1, b8 = jj & 1;
      float ar = b8 ? g1r[8] : g0r[8], ai = b8 ? g1i[8] : g0i[8];
      float Pr = m67r[q] * ar - m67i[q] * ai;
      float Pi = m67r[q] * ai + m67i[q] * ar;
      re[jj] = Pr * g9r - Pi * g9i;
      im[jj] = Pr * g9i + Pi * g9r;
    }
  }

  // ---- layer 2: Rots conjugated by PHI ----
#pragma unroll
  for (int w = 0; w < 10; ++w)
    rot2_wire(w, re, im, lane, p5, &Ulds[w][0]);

  // ---- features in the PHI^2 frame, folded into head dot-product ----
  f2 Sv = (f2){0.f, 0.f}, t6 = (f2){0.f, 0.f}, t7 = (f2){0.f, 0.f},
     t8 = (f2){0.f, 0.f};
  float t9 = 0.f;
#pragma unroll
  for (int jj = 0; jj < 8; ++jj) {
    f2 pf = re[jj] * re[jj] + im[jj] * im[jj];
    Sv += pf;
    t6 += (jj & 4) ? -pf : pf;
    t7 += (jj & 2) ? -pf : pf;
    t8 += ((__builtin_popcount(jj & 5) & 1)) ? -pf : pf;
    t9 += ((jj & 2) ? -1.f : 1.f) * (pf.x - pf.y);
  }
  const bool pl32 = (lane & 32) != 0, pl16 = (lane & 16) != 0;
  const bool pl40 = (__popc(lane & 40) & 1) != 0;
  const bool pl20 = (__popc(lane & 20) & 1) != 0;
  const bool pl42 = (__popc(lane & 42) & 1) != 0;
  const bool pl21 = (__popc(lane & 21) & 1) != 0;
  const float S_ = Sv.x + Sv.y;
  // fold wires 0..5 Z signs into one coefficient
  float zsum = (pl32 ? -hw[0] : hw[0]) + (pl16 ? -hw[1] : hw[1]) +
               (pl40 ? -hw[2] : hw[2]) + (pl20 ? -hw[3] : hw[3]) +
               (pl42 ? -hw[4] : hw[4]) + (pl21 ? -hw[5] : hw[5]);
  float acc = zsum * S_;
  const float t6_ = t6.x + t6.y, t7_ = t7.x + t7.y, t8_ = t8.x + t8.y;
  acc += hw[6] * (pl42 ? -t6_ : t6_);
  acc += hw[7] * (pl21 ? -t7_ : t7_);
  acc += hw[8] * (pl42 ? -t8_ : t8_);
  acc += hw[9] * (pl21 ? -t9 : t9);

  // X_w, wires 0..3: two-bit lane masks 40,20,10,5
  acc += hw[10] * xfeat_lane<40>(re, im);
  acc += hw[11] * xfeat_lane<20>(re, im);
  acc += hw[12] * xfeat_lane<10>(re, im);
  acc += hw[13] * xfeat_lane<5>(re, im);
  // X_4: lane bit1 ^ slot bit2;  X_5: lane bit0 ^ slot bit1
  {
    f2 x4 = (f2){0.f, 0.f}, x5 = (f2){0.f, 0.f};
#pragma unroll
    for (int jj = 0; jj < 8; ++jj) {
      x4 += re[jj] * partner2<2>(re[jj ^ 4]) + im[jj] * partner2<2>(im[jj ^ 4]);
      x5 += re[jj] * partner2<1>(re[jj ^ 2]) + im[jj] * partner2<1>(im[jj ^ 2]);
    }
    acc += hw[14] * (x4.x + x4.y);
    acc += hw[15] * (x5.x + x5.y);
  }
  // X_6: slots jj^5;  X_7: slots jj^2 + comp;  X_8: slots jj^1;  X_9: comp
  {
    f2 x6 = (f2){0.f, 0.f}, x7 = (f2){0.f, 0.f}, x8 = (f2){0.f, 0.f};
    float x9 = 0.f;
#pragma unroll
    for (int jj = 0; jj < 8; ++jj) {
      x6 += re[jj] * re[jj ^ 5] + im[jj] * im[jj ^ 5];
      x7 += re[jj] * swp(re[jj ^ 2]) + im[jj] * swp(im[jj ^ 2]);
      x8 += re[jj] * re[jj ^ 1] + im[jj] * im[jj ^ 1];
      x9 += re[jj].x * re[jj].y + im[jj].x * im[jj].y;
    }
    acc += hw[16] * (x6.x + x6.y);
    acc += hw[17] * (x7.x + x7.y);
    acc += hw[18] * (x8.x + x8.y);
    acc += hw[19] * (2.f * x9);
  }

  // butterfly reduction over the wave (verified primitives)
  acc += partner<32>(acc);
  acc += partner<16>(acc);
  acc += partner<8>(acc);
  acc += partner<4>(acc);
  acc += partner<2>(acc);
  acc += partner<1>(acc);
  if (lane == 0 && b < Bn) out[b] = acc + hb[0];
}

extern "C" void kernel_launch(void* const* d_in, const int* in_sizes, int n_in,
                              void* d_out, int out_size, void* d_ws, size_t ws_size,
                              hipStream_t stream) {
  const float* x      = (const float*)d_in[0];
  const float* params = (const float*)d_in[1];
  const float* hw     = (const float*)d_in[2];
  const float* hb     = (const float*)d_in[3];
  float* out = (float*)d_out;
  const int B = in_sizes[0] / 10;
  const int blocks = (B + 3) / 4;  // 4 waves/block, 1 sample/wave
  qreg_kernel<<<blocks, 256, 0, stream>>>(x, params, hw, hb, out, B);
}

// Round 15
// 21.716 us; speedup vs baseline: 1.0103x; 1.0103x over previous
//
#include <hip/hip_runtime.h>

#define DEV __device__ __forceinline__

// One wave (64 lanes) simulates one sample's 1024-amplitude state.
// flat idx = lane*16 + j ; wire w <-> flat bit (9-w):
//   wires 0..5 -> lane bits 5..0 (masks 32,16,8,4,2,1)
//   wires 6..8 -> packed-slot jj bits 2..0 (masks 4,2,1);  wire 9 -> component
// State: f2 re[8], im[8] (packed fp32, v_pk_fma_f32 full-rate).
//
// R10: CNOT chains never materialized (PHI frame change).
// R11: wave-uniform trig/matrix building once per block into LDS.
// R13: layer-1 Rots folded into the encoding product state.
// R15: DPP conversions (masks 3,6,10,5) + tree product build + Z fold,
//      WITHOUT the R14 launch_bounds(256,4) register cap (prime regressor).

typedef float f2 __attribute__((ext_vector_type(2)));

DEV float shx(float v, int m) { return __shfl_xor(v, m, 64); }

template <int CTRL>
DEV float dppx(float x) {
  int xi = __builtin_bit_cast(int, x);
  return __builtin_bit_cast(
      float, __builtin_amdgcn_update_dpp(xi, xi, CTRL, 0xF, 0xF, false));
}
template <int OFS>
DEV float swz(float x) {
  return __builtin_bit_cast(
      float, __builtin_amdgcn_ds_swizzle(__builtin_bit_cast(int, x), OFS));
}

// DPP ctrls: quad_perm xor1=0xB1, xor2=0x4E, xor3=0x1B;
//            row_ror:8 = 0x128 (xor8); row_half_mirror = 0x141 (xor7).

template <int M>  // scalar value at lane^M (single-bit masks)
DEV float partner(float x) {
  if constexpr (M == 32) return shx(x, 32);
  else if constexpr (M == 16) return swz<0x401F>(x);
  else if constexpr (M == 8) return dppx<0x128>(x);
  else if constexpr (M == 4) return swz<0x101F>(x);
  else if constexpr (M == 2) return dppx<0x4E>(x);
  else return dppx<0xB1>(x);
}
template <int M>
DEV f2 partner2(f2 v) { return (f2){partner<M>(v.x), partner<M>(v.y)}; }

template <int XM>  // generic lane-xor exchange (multi-bit masks)
DEV float lanex(float x) {
  if constexpr (XM == 48) return shx(x, 48);
  else if constexpr (XM == 40) return shx(x, 40);
  else if constexpr (XM == 24) return swz<0x601F>(x);
  else if constexpr (XM == 20) return swz<0x501F>(x);
  else if constexpr (XM == 12) return swz<0x301F>(x);
  else if constexpr (XM == 10) return dppx<0x4E>(dppx<0x128>(x));   // xor8∘xor2
  else if constexpr (XM == 6)  return dppx<0xB1>(dppx<0x141>(x));   // xor7∘xor1
  else if constexpr (XM == 5)  return dppx<0x4E>(dppx<0x141>(x));   // xor7∘xor2
  else if constexpr (XM == 3)  return dppx<0x1B>(x);                // quad xor3
}
template <int XM>
DEV f2 lanex2(f2 v) { return (f2){lanex<XM>(v.x), lanex<XM>(v.y)}; }

DEV f2 swp(f2 v) { return (f2){v.y, v.x}; }

// ================= layer-2 gates (conjugated by PHI, verified R10/R12) =======

template <int XM, int SELM>
DEV void rot2_lane(f2 (&re)[8], f2 (&im)[8], int lane,
                   float u00r, float u00i, float u01r, float u01i,
                   float u10r, float u10i, float u11r, float u11i) {
  const bool hi = (__popc(lane & SELM) & 1) != 0;
  float Dor = hi ? u11r : u00r, Doi = hi ? u11i : u00i;
  float Dpr = hi ? u10r : u01r, Dpi = hi ? u10i : u01i;
#pragma unroll
  for (int jj = 0; jj < 8; ++jj) {
    f2 pr = lanex2<XM>(re[jj]), pi = lanex2<XM>(im[jj]);
    f2 nr = Dor * re[jj] - Doi * im[jj] + Dpr * pr - Dpi * pi;
    f2 ni = Dor * im[jj] + Doi * re[jj] + Dpr * pi + Dpi * pr;
    re[jj] = nr; im[jj] = ni;
  }
}

DEV void rot2_w5(f2 (&re)[8], f2 (&im)[8], bool p5,
                 float u00r, float u00i, float u01r, float u01i,
                 float u10r, float u10i, float u11r, float u11i) {
  float Dor = p5 ? u11r : u00r, Doi = p5 ? u11i : u00i;
  float Dpr = p5 ? u10r : u01r, Dpi = p5 ? u10i : u01i;
  f2 o_r[8], o_i[8];
#pragma unroll
  for (int jj = 0; jj < 8; ++jj) { o_r[jj] = re[jj]; o_i[jj] = im[jj]; }
#pragma unroll
  for (int jj = 0; jj < 8; ++jj) {
    const int k = jj ^ 4;
    f2 pr = partner2<1>(o_r[k]), pi = partner2<1>(o_i[k]);
    re[jj] = Dor * o_r[jj] - Doi * o_i[jj] + Dpr * pr - Dpi * pi;
    im[jj] = Dor * o_i[jj] + Doi * o_r[jj] + Dpr * pi + Dpi * pr;
  }
}

template <int M2, int CLS>
DEV void rot2_local(f2 (&re)[8], f2 (&im)[8], bool p5,
                    float u00r, float u00i, float u01r, float u01i,
                    float u10r, float u10i, float u11r, float u11i) {
  const float D0or = p5 ? u11r : u00r, D0oi = p5 ? u11i : u00i;
  const float D0pr = p5 ? u10r : u01r, D0pi = p5 ? u10i : u01i;
  const float D1or = p5 ? u00r : u11r, D1oi = p5 ? u00i : u11i;
  const float D1pr = p5 ? u01r : u10r, D1pi = p5 ? u01i : u10i;
  f2 o_r[8], o_i[8];
#pragma unroll
  for (int jj = 0; jj < 8; ++jj) { o_r[jj] = re[jj]; o_i[jj] = im[jj]; }
#pragma unroll
  for (int jj = 0; jj < 8; ++jj) {
    const int k = jj ^ M2;
    const bool c1 = (__builtin_popcount(jj & CLS) & 1) != 0;
    const float Dor = c1 ? D1or : D0or, Doi = c1 ? D1oi : D0oi;
    const float Dpr = c1 ? D1pr : D0pr, Dpi = c1 ? D1pi : D0pi;
    re[jj] = Dor * o_r[jj] - Doi * o_i[jj] + Dpr * o_r[k] - Dpi * o_i[k];
    im[jj] = Dor * o_i[jj] + Doi * o_r[jj] + Dpr * o_i[k] + Dpi * o_r[k];
  }
}

DEV void rot2_w8(f2 (&re)[8], f2 (&im)[8], bool p5,
                 float u00r, float u00i, float u01r, float u01i,
                 float u10r, float u10i, float u11r, float u11i) {
  const float D0or = p5 ? u11r : u00r, D0oi = p5 ? u11i : u00i;
  const float D0pr = p5 ? u10r : u01r, D0pi = p5 ? u10i : u01i;
  const float D1or = p5 ? u00r : u11r, D1oi = p5 ? u00i : u11i;
  const float D1pr = p5 ? u01r : u10r, D1pi = p5 ? u01i : u10i;
  f2 o_r[8], o_i[8];
#pragma unroll
  for (int jj = 0; jj < 8; ++jj) { o_r[jj] = re[jj]; o_i[jj] = im[jj]; }
#pragma unroll
  for (int jj = 0; jj < 8; ++jj) {
    const int k = jj ^ 1;
    const bool c1 = (__builtin_popcount(jj & 7) & 1) != 0;
    const float Dor = c1 ? D1or : D0or, Doi = c1 ? D1oi : D0oi;
    const float Dpr = c1 ? D1pr : D0pr, Dpi = c1 ? D1pi : D0pi;
    f2 pr = swp(o_r[k]), pi = swp(o_i[k]);
    re[jj] = Dor * o_r[jj] - Doi * o_i[jj] + Dpr * pr - Dpi * pi;
    im[jj] = Dor * o_i[jj] + Doi * o_r[jj] + Dpr * pi + Dpi * pr;
  }
}

DEV void rot2_w9(f2 (&re)[8], f2 (&im)[8], bool p5,
                 float u00r, float u00i, float u01r, float u01i,
                 float u10r, float u10i, float u11r, float u11i) {
  const f2 Vor0 = p5 ? (f2){u11r, u00r} : (f2){u00r, u11r};
  const f2 Voi0 = p5 ? (f2){u11i, u00i} : (f2){u00i, u11i};
  const f2 Vpr0 = p5 ? (f2){u10r, u01r} : (f2){u01r, u10r};
  const f2 Vpi0 = p5 ? (f2){u10i, u01i} : (f2){u01i, u10i};
  const f2 Vor1 = p5 ? (f2){u00r, u11r} : (f2){u11r, u00r};
  const f2 Voi1 = p5 ? (f2){u00i, u11i} : (f2){u11i, u00i};
  const f2 Vpr1 = p5 ? (f2){u01r, u10r} : (f2){u10r, u01r};
  const f2 Vpi1 = p5 ? (f2){u01i, u10i} : (f2){u10i, u01i};
#pragma unroll
  for (int jj = 0; jj < 8; ++jj) {
    const bool c1 = (__builtin_popcount(jj) & 1) != 0;
    const f2 Vor = c1 ? Vor1 : Vor0, Voi = c1 ? Voi1 : Voi0;
    const f2 Vpr = c1 ? Vpr1 : Vpr0, Vpi = c1 ? Vpi1 : Vpi0;
    f2 sr = swp(re[jj]), si = swp(im[jj]);
    f2 nr = Vor * re[jj] - Voi * im[jj] + Vpr * sr - Vpi * si;
    f2 ni = Vor * im[jj] + Voi * re[jj] + Vpr * si + Vpi * sr;
    re[jj] = nr; im[jj] = ni;
  }
}

// ================= U-matrix build =============================================

DEV void make_u(const float* __restrict__ pp, float (&u)[8]) {
  // PennyLane Rot = RZ(om) @ RY(th) @ RZ(ph)
  float ph = pp[0], th = pp[1], om = pp[2];
  float s, c;   __sincosf(0.5f * th, &s, &c);
  float sa, ca; __sincosf(0.5f * (ph + om), &sa, &ca);
  float sb, cb; __sincosf(0.5f * (ph - om), &sb, &cb);
  u[0] = c * ca;  u[1] = -c * sa;   // u00
  u[2] = -s * cb; u[3] = -s * sb;   // u01
  u[4] = s * cb;  u[5] = -s * sb;   // u10
  u[6] = c * ca;  u[7] = c * sa;    // u11
}

DEV void rot2_wire(int w, f2 (&re)[8], f2 (&im)[8], int lane, bool p5,
                   const float* u) {
  float u00r = u[0], u00i = u[1], u01r = u[2], u01i = u[3];
  float u10r = u[4], u10i = u[5], u11r = u[6], u11i = u[7];
  switch (w) {
    case 0: rot2_lane<48, 32>(re, im, lane, u00r, u00i, u01r, u01i, u10r, u10i, u11r, u11i); break;
    case 1: rot2_lane<24, 48>(re, im, lane, u00r, u00i, u01r, u01i, u10r, u10i, u11r, u11i); break;
    case 2: rot2_lane<12, 56>(re, im, lane, u00r, u00i, u01r, u01i, u10r, u10i, u11r, u11i); break;
    case 3: rot2_lane<6, 60>(re, im, lane, u00r, u00i, u01r, u01i, u10r, u10i, u11r, u11i); break;
    case 4: rot2_lane<3, 62>(re, im, lane, u00r, u00i, u01r, u01i, u10r, u10i, u11r, u11i); break;
    case 5: rot2_w5(re, im, p5, u00r, u00i, u01r, u01i, u10r, u10i, u11r, u11i); break;
    case 6: rot2_local<6, 4>(re, im, p5, u00r, u00i, u01r, u01i, u10r, u10i, u11r, u11i); break;
    case 7: rot2_local<3, 6>(re, im, p5, u00r, u00i, u01r, u01i, u10r, u10i, u11r, u11i); break;
    case 8: rot2_w8(re, im, p5, u00r, u00i, u01r, u01i, u10r, u10i, u11r, u11i); break;
    case 9: rot2_w9(re, im, p5, u00r, u00i, u01r, u01i, u10r, u10i, u11r, u11i); break;
  }
}

// ================= X features (PHI^2 frame, verified R10/R12) ================

template <int XM>
DEV float xfeat_lane(const f2 (&re)[8], const f2 (&im)[8]) {
  f2 t = (f2){0.f, 0.f};
#pragma unroll
  for (int jj = 0; jj < 8; ++jj)
    t += re[jj] * lanex2<XM>(re[jj]) + im[jj] * lanex2<XM>(im[jj]);
  return t.x + t.y;
}

// ================= kernel ====================================================

__global__ __launch_bounds__(256) void qreg_kernel(
    const float* __restrict__ x,      // (B, 10)
    const float* __restrict__ params, // (60,)
    const float* __restrict__ hw,     // (20,)
    const float* __restrict__ hb,     // (1,)
    float* __restrict__ out,          // (B,)
    int Bn) {
  const int tid = threadIdx.x;
  const int lane = tid & 63;
  const int wv = tid >> 6;
  const int b = blockIdx.x * 4 + wv;
  const bool p5 = (__popc(lane & 63) & 1) != 0;

  // ---- once-per-block precompute (LDS broadcast) ----
  __shared__ __align__(16) float Ulds[10][8];   // layer-2 Rot matrices
  __shared__ __align__(16) float Enc[4][10][4]; // per-sample g_w = U_w1 @ (c,s)

  if (tid < 10) {
    float u[8];
    make_u(params + (10 + tid) * 3, u);
#pragma unroll
    for (int k = 0; k < 8; ++k) Ulds[tid][k] = u[k];
  }
  if (tid >= 64 && tid < 104) {
    const int t = tid - 64;
    const int s = t / 10, w = t % 10;
    int bs = blockIdx.x * 4 + s;
    if (bs >= Bn) bs = Bn - 1;
    float sn, cs;
    __sincosf(0.5f * x[bs * 10 + w], &sn, &cs);
    float u[8];
    make_u(params + w * 3, u);  // layer-1 U for this wire
    // g = U @ (cs, sn)^T  (cs,sn real)
    Enc[s][w][0] = u[0] * cs + u[2] * sn;  // g0r
    Enc[s][w][1] = u[1] * cs + u[3] * sn;  // g0i
    Enc[s][w][2] = u[4] * cs + u[6] * sn;  // g1r
    Enc[s][w][3] = u[5] * cs + u[7] * sn;  // g1i
  }
  __syncthreads();

  f2 re[8], im[8];

  // ---- product state = encoding ⊗ layer-1 (complex factors) ----
  {
    float g0r[10], g0i[10], g1r[10], g1i[10];
#pragma unroll
    for (int w = 0; w < 10; ++w) {
      g0r[w] = Enc[wv][w][0]; g0i[w] = Enc[wv][w][1];
      g1r[w] = Enc[wv][w][2]; g1i[w] = Enc[wv][w][3];
    }
    // lane factor L (complex), tree-reassociated: wires 0..5 <-> lane bits 5..0
    float sr[6], si[6];
#pragma unroll
    for (int w = 0; w < 6; ++w) {
      const int m = 1 << (5 - w);
      sr[w] = (lane & m) ? g1r[w] : g0r[w];
      si[w] = (lane & m) ? g1i[w] : g0i[w];
    }
    float a01r = sr[0] * sr[1] - si[0] * si[1];
    float a01i = sr[0] * si[1] + si[0] * sr[1];
    float a23r = sr[2] * sr[3] - si[2] * si[3];
    float a23i = sr[2] * si[3] + si[2] * sr[3];
    float a45r = sr[4] * sr[5] - si[4] * si[5];
    float a45i = sr[4] * si[5] + si[4] * sr[5];
    float b03r = a01r * a23r - a01i * a23i;
    float b03i = a01r * a23i + a01i * a23r;
    float Lr = b03r * a45r - b03i * a45i;
    float Li = b03r * a45i + b03i * a45r;
    // m6[b6] = L * g6[b6]
    float m6r[2], m6i[2];
#pragma unroll
    for (int bq = 0; bq < 2; ++bq) {
      float ar = bq ? g1r[6] : g0r[6], ai = bq ? g1i[6] : g0i[6];
      m6r[bq] = Lr * ar - Li * ai;
      m6i[bq] = Lr * ai + Li * ar;
    }
    // m67[b6*2+b7] = m6[b6] * g7[b7]
    float m67r[4], m67i[4];
#pragma unroll
    for (int q = 0; q < 4; ++q) {
      const int b6 = q >> 1, b7 = q & 1;
      float ar = b7 ? g1r[7] : g0r[7], ai = b7 ? g1i[7] : g0i[7];
      m67r[q] = m6r[b6] * ar - m6i[b6] * ai;
      m67i[q] = m6r[b6] * ai + m6i[b6] * ar;
    }
    // P[jj] = m67[jj>>1] * g8[jj&1]; amp[jj] = P[jj] * g9(component pair)
    const f2 g9r = (f2){g0r[9], g1r[9]}, g9i = (f2){g0i[9], g1i[9]};
#pragma unroll
    for (int jj = 0; jj < 8; ++jj) {
      const int q = jj >> 1, b8 = jj & 1;
      float ar = b8 ? g1r[8] : g0r[8], ai = b8 ? g1i[8] : g0i[8];
      float Pr = m67r[q] * ar - m67i[q] * ai;
      float Pi = m67r[q] * ai + m67i[q] * ar;
      re[jj] = Pr * g9r - Pi * g9i;
      im[jj] = Pr * g9i + Pi * g9r;
    }
  }

  // ---- layer 2: Rots conjugated by PHI ----
#pragma unroll
  for (int w = 0; w < 10; ++w)
    rot2_wire(w, re, im, lane, p5, &Ulds[w][0]);

  // ---- features in the PHI^2 frame, folded into head dot-product ----
  f2 Sv = (f2){0.f, 0.f}, t6 = (f2){0.f, 0.f}, t7 = (f2){0.f, 0.f},
     t8 = (f2){0.f, 0.f};
  float t9 = 0.f;
#pragma unroll
  for (int jj = 0; jj < 8; ++jj) {
    f2 pf = re[jj] * re[jj] + im[jj] * im[jj];
    Sv += pf;
    t6 += (jj & 4) ? -pf : pf;
    t7 += (jj & 2) ? -pf : pf;
    t8 += ((__builtin_popcount(jj & 5) & 1)) ? -pf : pf;
    t9 += ((jj & 2) ? -1.f : 1.f) * (pf.x - pf.y);
  }
  const bool pl32 = (lane & 32) != 0, pl16 = (lane & 16) != 0;
  const bool pl40 = (__popc(lane & 40) & 1) != 0;
  const bool pl20 = (__popc(lane & 20) & 1) != 0;
  const bool pl42 = (__popc(lane & 42) & 1) != 0;
  const bool pl21 = (__popc(lane & 21) & 1) != 0;
  const float S_ = Sv.x + Sv.y;
  // fold wires 0..5 Z signs into one coefficient
  float zsum = (pl32 ? -hw[0] : hw[0]) + (pl16 ? -hw[1] : hw[1]) +
               (pl40 ? -hw[2] : hw[2]) + (pl20 ? -hw[3] : hw[3]) +
               (pl42 ? -hw[4] : hw[4]) + (pl21 ? -hw[5] : hw[5]);
  float acc = zsum * S_;
  const float t6_ = t6.x + t6.y, t7_ = t7.x + t7.y, t8_ = t8.x + t8.y;
  acc += hw[6] * (pl42 ? -t6_ : t6_);
  acc += hw[7] * (pl21 ? -t7_ : t7_);
  acc += hw[8] * (pl42 ? -t8_ : t8_);
  acc += hw[9] * (pl21 ? -t9 : t9);

  // X_w, wires 0..3: two-bit lane masks 40,20,10,5
  acc += hw[10] * xfeat_lane<40>(re, im);
  acc += hw[11] * xfeat_lane<20>(re, im);
  acc += hw[12] * xfeat_lane<10>(re, im);
  acc += hw[13] * xfeat_lane<5>(re, im);
  // X_4: lane bit1 ^ slot bit2;  X_5: lane bit0 ^ slot bit1
  {
    f2 x4 = (f2){0.f, 0.f}, x5 = (f2){0.f, 0.f};
#pragma unroll
    for (int jj = 0; jj < 8; ++jj) {
      x4 += re[jj] * partner2<2>(re[jj ^ 4]) + im[jj] * partner2<2>(im[jj ^ 4]);
      x5 += re[jj] * partner2<1>(re[jj ^ 2]) + im[jj] * partner2<1>(im[jj ^ 2]);
    }
    acc += hw[14] * (x4.x + x4.y);
    acc += hw[15] * (x5.x + x5.y);
  }
  // X_6: slots jj^5;  X_7: slots jj^2 + comp;  X_8: slots jj^1;  X_9: comp
  {
    f2 x6 = (f2){0.f, 0.f}, x7 = (f2){0.f, 0.f}, x8 = (f2){0.f, 0.f};
    float x9 = 0.f;
#pragma unroll
    for (int jj = 0; jj < 8; ++jj) {
      x6 += re[jj] * re[jj ^ 5] + im[jj] * im[jj ^ 5];
      x7 += re[jj] * swp(re[jj ^ 2]) + im[jj] * swp(im[jj ^ 2]);
      x8 += re[jj] * re[jj ^ 1] + im[jj] * im[jj ^ 1];
      x9 += re[jj].x * re[jj].y + im[jj].x * im[jj].y;
    }
    acc += hw[16] * (x6.x + x6.y);
    acc += hw[17] * (x7.x + x7.y);
    acc += hw[18] * (x8.x + x8.y);
    acc += hw[19] * (2.f * x9);
  }

  // butterfly reduction over the wave (verified primitives)
  acc += partner<32>(acc);
  acc += partner<16>(acc);
  acc += partner<8>(acc);
  acc += partner<4>(acc);
  acc += partner<2>(acc);
  acc += partner<1>(acc);
  if (lane == 0 && b < Bn) out[b] = acc + hb[0];
}

extern "C" void kernel_launch(void* const* d_in, const int* in_sizes, int n_in,
                              void* d_out, int out_size, void* d_ws, size_t ws_size,
                              hipStream_t stream) {
  const float* x      = (const float*)d_in[0];
  const float* params = (const float*)d_in[1];
  const float* hw     = (const float*)d_in[2];
  const float* hb     = (const float*)d_in[3];
  float* out = (float*)d_out;
  const int B = in_sizes[0] / 10;
  const int blocks = (B + 3) / 4;  // 4 waves/block, 1 sample/wave
  qreg_kernel<<<blocks, 256, 0, stream>>>(x, params, hw, hb, out, B);
}

// Round 16
// 12.070 us; speedup vs baseline: 1.8177x; 1.7991x over previous
//
#include <hip/hip_runtime.h>

#define DEV __device__ __forceinline__

// ============================================================================
// Transfer-matrix (MPS) formulation. One THREAD per sample.
//
// Pipeline: psi_f = PHI . L2 . PHI . (prod-state after encode+L1)
//   - product state: amp = prod_w g_w[bit_w],  g_w = U1_w @ (cos x_w/2, sin)
//     [R13-verified]
//   - observables conjugated through the 2nd CNOT chain (exact Pauli algebra):
//       Z_w -> Z_0 Z_1 ... Z_w          (prefix string)
//       X_w -> X_w X_{w+1}  (w<=8),  X_9 -> X_9
//     [cross-checked: chain applied twice reproduces R10's verified PHI^2
//      parities {u<=w, w-u even} and masks e_w ^ e_{w+2}]
//   - through L2: Z -> ZM_v = U2_v^dag Z U2_v, X -> XM_v (2x2 Hermitian)
//   - expectation under PHI.(prod-state): psi1[c] = prod_v g_v[c_v ^ c_{v-1}]
//     => 4-state transfer contraction over wires v=0..9, carried state
//     (a,b) = (c_{v-1}, c'_{v-1}):
//       T^M[(a,b)->(c,d)] = conj(g[c^a]) * M[c,d] * g[d^b]
//     f  : all-I vector (stays REAL & DIAGONAL: I-transfer kills off-diag)
//     zf : all-ZM prefix vector (gives every Z_w when closed at step w)
//     px : pending X pair (XM at step v, XM at step v+1, then done)
//     A  : weighted accumulator of completed features, propagated by T^I
//   Final: out = Re(sum A) + hw[19]*Re(sum px_after_step9) + hb.
// ============================================================================

struct cpx { float r, i; };
DEV cpx cmul (cpx a, cpx b) { return {a.r*b.r - a.i*b.i, a.r*b.i + a.i*b.r}; }
DEV cpx cjmul(cpx a, cpx b) { return {a.r*b.r + a.i*b.i, a.r*b.i - a.i*b.r}; } // conj(a)*b
DEV cpx cadd (cpx a, cpx b) { return {a.r + b.r, a.i + b.i}; }
DEV cpx csc  (cpx a, float s) { return {a.r*s, a.i*s}; }
DEV cpx cconj(cpx a) { return {a.r, -a.i}; }

DEV void make_u(const float* __restrict__ pp, float (&u)[8]) {
  // PennyLane Rot = RZ(om) @ RY(th) @ RZ(ph)   [R13-verified]
  float ph = pp[0], th = pp[1], om = pp[2];
  float s, c;   __sincosf(0.5f * th, &s, &c);
  float sa, ca; __sincosf(0.5f * (ph + om), &sa, &ca);
  float sb, cb; __sincosf(0.5f * (ph - om), &sb, &cb);
  u[0] = c * ca;  u[1] = -c * sa;   // u00
  u[2] = -s * cb; u[3] = -s * sb;   // u01
  u[4] = s * cb;  u[5] = -s * sb;   // u10
  u[6] = c * ca;  u[7] = c * sa;    // u11
}

__global__ __launch_bounds__(64) void qreg_kernel(
    const float* __restrict__ x,      // (B, 10)
    const float* __restrict__ params, // (60,)
    const float* __restrict__ hw,     // (20,)
    const float* __restrict__ hb,     // (1,)
    float* __restrict__ out,          // (B,)
    int Bn) {
  const int tid = threadIdx.x;
  const int b = blockIdx.x * 64 + tid;

  __shared__ __align__(16) float U1[10][8];  // layer-1 Rot matrices
  __shared__ __align__(16) float ZM[10][4];  // {m00, m11, m01r, m01i} (Hermitian)
  __shared__ __align__(16) float XM[10][4];

  if (tid < 10) {
    // layer-2 matrices -> conjugated Pauli observables
    float u[8]; make_u(params + (10 + tid) * 3, u);
    cpx u00 = {u[0], u[1]}, u01 = {u[2], u[3]};
    cpx u10 = {u[4], u[5]}, u11 = {u[6], u[7]};
    float n00 = u00.r*u00.r + u00.i*u00.i, n01 = u01.r*u01.r + u01.i*u01.i;
    float n10 = u10.r*u10.r + u10.i*u10.i, n11 = u11.r*u11.r + u11.i*u11.i;
    // ZM = U^dag Z U : [[ |u00|^2-|u10|^2 , conj(u00)u01 - conj(u10)u11 ], [h.c., |u01|^2-|u11|^2]]
    cpx zm01 = cadd(cjmul(u00, u01), csc(cjmul(u10, u11), -1.f));
    ZM[tid][0] = n00 - n10; ZM[tid][1] = n01 - n11;
    ZM[tid][2] = zm01.r;    ZM[tid][3] = zm01.i;
    // XM = U^dag X U : [[ 2Re(conj(u00)u10) , conj(u00)u11 + conj(u10)u01 ], [h.c., 2Re(conj(u01)u11)]]
    cpx xm01 = cadd(cjmul(u00, u11), cjmul(u10, u01));
    XM[tid][0] = 2.f * (u00.r*u10.r + u00.i*u10.i);
    XM[tid][1] = 2.f * (u01.r*u11.r + u01.i*u11.i);
    XM[tid][2] = xm01.r; XM[tid][3] = xm01.i;
  } else if (tid >= 16 && tid < 26) {
    const int w = tid - 16;
    float u[8]; make_u(params + w * 3, u);
#pragma unroll
    for (int k = 0; k < 8; ++k) U1[w][k] = u[k];
  }
  __syncthreads();
  if (b >= Bn) return;

  float xv[10];
#pragma unroll
  for (int w = 0; w < 10; ++w) xv[w] = x[b * 10 + w];

  cpx A00{0,0}, A01{0,0}, A10{0,0}, A11{0,0};   // accumulator
  cpx z00{1.f,0}, z01{0,0}, z10{0,0}, z11{0,0}; // zf (starts at e_(0,0))
  cpx p00{0,0}, p01{0,0}, p10{0,0}, p11{0,0};   // pending X pair
  float f0 = 1.f, f1 = 0.f;                     // all-I vector (real diagonal)

#pragma unroll
  for (int v = 0; v < 10; ++v) {
    float sn, cs; __sincosf(0.5f * xv[v], &sn, &cs);
    cpx g0 = {U1[v][0]*cs + U1[v][2]*sn, U1[v][1]*cs + U1[v][3]*sn};
    cpx g1 = {U1[v][4]*cs + U1[v][6]*sn, U1[v][5]*cs + U1[v][7]*sn};
    float n0 = g0.r*g0.r + g0.i*g0.i, n1 = g1.r*g1.r + g1.i*g1.i;
    const float xm00 = XM[v][0], xm11 = XM[v][1];
    const cpx xm01 = {XM[v][2], XM[v][3]};

    // ---- A: identity transfer (output is diagonal) ----
    // t1[c][b] = conj(g[c])A[0][b] + conj(g[c^1])A[1][b]
    cpx t100 = cadd(cjmul(g0, A00), cjmul(g1, A10));
    cpx t101 = cadd(cjmul(g0, A01), cjmul(g1, A11));
    cpx t110 = cadd(cjmul(g1, A00), cjmul(g0, A10));
    cpx t111 = cadd(cjmul(g1, A01), cjmul(g0, A11));
    cpx nA00 = cadd(cmul(g0, t100), cmul(g1, t101));
    cpx nA11 = cadd(cmul(g1, t110), cmul(g0, t111));
    cpx nA01{0,0}, nA10{0,0};

    // ---- complete pending X_{v-1}: apply T^{XM_v} to px, add with hw[10+v-1] ----
    if (v >= 1) {
      cpx s100 = cadd(cjmul(g0, p00), cjmul(g1, p10));
      cpx s101 = cadd(cjmul(g0, p01), cjmul(g1, p11));
      cpx s110 = cadd(cjmul(g1, p00), cjmul(g0, p10));
      cpx s111 = cadd(cjmul(g1, p01), cjmul(g0, p11));
      cpx q00 = cadd(cmul(g0, s100), cmul(g1, s101));
      cpx q01 = cadd(cmul(g1, s100), cmul(g0, s101));
      cpx q10 = cadd(cmul(g0, s110), cmul(g1, s111));
      cpx q11 = cadd(cmul(g1, s110), cmul(g0, s111));
      const float w = hw[10 + v - 1];
      nA00 = cadd(nA00, csc(q00, xm00 * w));
      nA11 = cadd(nA11, csc(q11, xm11 * w));
      nA01 = cadd(nA01, csc(cmul(xm01, q01), w));
      nA10 = cadd(nA10, csc(cmul(cconj(xm01), q10), w));
    }

    // ---- start X_v from f (real diagonal): px = XM .* S ----
    {
      cpx h01 = cjmul(g0, g1);                      // conj(g0)*g1
      float S00 = n0 * f0 + n1 * f1;
      float S11 = n1 * f0 + n0 * f1;
      cpx S01 = cadd(csc(h01, f0), csc(cconj(h01), f1));
      cpx S10 = cconj(S01);
      p00 = {S00 * xm00, 0.f};
      p11 = {S11 * xm11, 0.f};
      p01 = cmul(xm01, S01);
      p10 = cmul(cconj(xm01), S10);
    }

    // ---- zf: transfer with ZM_v, then add completed Z_v with hw[v] ----
    {
      const float zm00 = ZM[v][0], zm11 = ZM[v][1];
      const cpx zm01 = {ZM[v][2], ZM[v][3]};
      cpx r100 = cadd(cjmul(g0, z00), cjmul(g1, z10));
      cpx r101 = cadd(cjmul(g0, z01), cjmul(g1, z11));
      cpx r110 = cadd(cjmul(g1, z00), cjmul(g0, z10));
      cpx r111 = cadd(cjmul(g1, z01), cjmul(g0, z11));
      cpx y00 = cadd(cmul(g0, r100), cmul(g1, r101));
      cpx y01 = cadd(cmul(g1, r100), cmul(g0, r101));
      cpx y10 = cadd(cmul(g0, r110), cmul(g1, r111));
      cpx y11 = cadd(cmul(g1, r110), cmul(g0, r111));
      z00 = csc(y00, zm00); z11 = csc(y11, zm11);
      z01 = cmul(zm01, y01); z10 = cmul(cconj(zm01), y10);
      const float w = hw[v];
      nA00 = cadd(nA00, csc(z00, w)); nA01 = cadd(nA01, csc(z01, w));
      nA10 = cadd(nA10, csc(z10, w)); nA11 = cadd(nA11, csc(z11, w));
    }

    A00 = nA00; A01 = nA01; A10 = nA10; A11 = nA11;
    const float nf0 = n0 * f0 + n1 * f1;
    const float nf1 = n1 * f0 + n0 * f1;
    f0 = nf0; f1 = nf1;
  }

  // X_9 is single-wire: px after step 9 IS the complete feature.
  const float res = A00.r + A01.r + A10.r + A11.r
                  + hw[19] * (p00.r + p01.r + p10.r + p11.r)
                  + hb[0];
  out[b] = res;
}

extern "C" void kernel_launch(void* const* d_in, const int* in_sizes, int n_in,
                              void* d_out, int out_size, void* d_ws, size_t ws_size,
                              hipStream_t stream) {
  const float* x      = (const float*)d_in[0];
  const float* params = (const float*)d_in[1];
  const float* hw     = (const float*)d_in[2];
  const float* hb     = (const float*)d_in[3];
  float* out = (float*)d_out;
  const int B = in_sizes[0] / 10;
  const int blocks = (B + 63) / 64;  // one THREAD per sample, 64-thread blocks
  qreg_kernel<<<blocks, 64, 0, stream>>>(x, params, hw, hb, out, B);
}